// Round 3
// baseline (577.187 us; speedup 1.0000x reference)
//
#include <hip/hip_runtime.h>
#include <hip/hip_fp16.h>

#define N_NODES 50000
#define HIDDEN  64
#define N_EDGES 1200000

#define BSHIFT 7                       // 128 nodes per bucket
#define BUKSZ  128
#define NBUK   391                     // ceil(50000/128)
#define GBIN   512                     // scatter blocks (2 blocks/CU)
#define PAD2   6144                    // csr capacity per bucket (avg 3072 + 16-align pads)
#define FWAVES 12500                   // fused-layer waves
#define FBLK   (FWAVES / 4)
#define NPW    4

typedef unsigned short ushort_t;
typedef _Float16 hf2 __attribute__((ext_vector_type(2)));

__device__ __forceinline__ float bcastf(float v, int k) {
    return __int_as_float(__builtin_amdgcn_readlane(__float_as_int(v), k));
}
__device__ __forceinline__ hf2 u2h(unsigned u) { union { unsigned u; hf2 h; } x; x.u = u; return x.h; }
__device__ __forceinline__ unsigned h2u(hf2 h) { union { hf2 h; unsigned u; } x; x.h = h; return x.u; }
__device__ __forceinline__ unsigned pkh(float a, float b) {   // 2xf32 -> packed f16 (v_cvt_pkrtz)
    __half2 h = __float22half2_rn(make_float2(a, b));
    union { __half2 h; unsigned u; } x; x.h = h; return x.u;
}
__device__ __forceinline__ ushort_t f2h(float a) {
    __half h = __float2half_rn(a);
    union { __half h; ushort_t u; } x; x.h = h; return x.u;
}
__device__ __forceinline__ void bfly(float4& a) {      // all lanes end with group-sum (xor16,32)
    a.x += __shfl_xor(a.x, 16); a.y += __shfl_xor(a.y, 16);
    a.z += __shfl_xor(a.z, 16); a.w += __shfl_xor(a.w, 16);
    a.x += __shfl_xor(a.x, 32); a.y += __shfl_xor(a.y, 32);
    a.z += __shfl_xor(a.z, 32); a.w += __shfl_xor(a.w, 32);
}
__device__ __forceinline__ hf2 sxor(hf2 v, int m) {    // f16x2 shfl_xor add helper
    return v + u2h((unsigned)__shfl_xor((int)h2u(v), m));
}

// ---------------- 1) init: cursor + W f16-pair packing ----------------
__global__ __launch_bounds__(512) void init_kernel(int* __restrict__ cursor,
                                                   const float* __restrict__ Wn2, const float* __restrict__ Ws2,
                                                   const float* __restrict__ Wn3, const float* __restrict__ Ws3,
                                                   const float* __restrict__ Wn4, const float* __restrict__ Ws4,
                                                   uint4* __restrict__ pw) {
    int b = blockIdx.x, tid = threadIdx.x;
    if (b == 0) {
        if (tid < NBUK) cursor[tid] = tid * PAD2;
    } else {
        int layer = b - 1;
        const float* Wn = (layer == 0) ? Wn2 : (layer == 1) ? Wn3 : Wn4;
        const float* Ws = (layer == 0) ? Ws2 : (layer == 1) ? Ws3 : Ws4;
        int kp = tid >> 4, q = tid & 15;           // tid < 512
        {
            const float4 a = *(const float4*)(Wn + (2 * kp) * 64 + 4 * q);
            const float4 c = *(const float4*)(Wn + (2 * kp + 1) * 64 + 4 * q);
            pw[layer * 1024 + tid] = make_uint4(pkh(a.x, c.x), pkh(a.y, c.y), pkh(a.z, c.z), pkh(a.w, c.w));
        }
        {
            const float4 a = *(const float4*)(Ws + (2 * kp) * 64 + 4 * q);
            const float4 c = *(const float4*)(Ws + (2 * kp + 1) * 64 + 4 * q);
            pw[layer * 1024 + 512 + tid] = make_uint4(pkh(a.x, c.x), pkh(a.y, c.y), pkh(a.z, c.z), pkh(a.w, c.w));
        }
    }
}

// ---------------- 2) scatter (R8-proven) ----------------
__global__ __launch_bounds__(256) void scatter_fused_kernel(const int* __restrict__ ei,
                                                            int* __restrict__ cursor,
                                                            int* __restrict__ tmp, int E) {
    __shared__ int h[NBUK];
    __shared__ int cur[NBUK];
    int tid = threadIdx.x;
    for (int b = tid; b < NBUK; b += 256) h[b] = 0;
    __syncthreads();
    for (int e = blockIdx.x * 256 + tid; e < E; e += GBIN * 256)
        atomicAdd(&h[ei[E + e] >> BSHIFT], 1);
    __syncthreads();
    for (int b = tid; b < NBUK; b += 256) cur[b] = atomicAdd(&cursor[b], h[b]);
    __syncthreads();
    for (int e = blockIdx.x * 256 + tid; e < E; e += GBIN * 256) {
        int src = ei[e];
        int dst = ei[E + e];
        int p = atomicAdd(&cur[dst >> BSHIFT], 1);
        tmp[p] = src | ((dst & (BUKSZ - 1)) << 16);
    }
}

// ---------------- 3) bucketize (16-aligned, pad=50000) || gemm1 ----------------
__global__ __launch_bounds__(512) void bucketize_kernel(const int* __restrict__ tmp,
                                                        const int* __restrict__ cursor,
                                                        int2* __restrict__ row_info,
                                                        ushort_t* __restrict__ csr,
                                                        const float* __restrict__ x,
                                                        const float* __restrict__ Wrel,
                                                        const float* __restrict__ Wroot,
                                                        const float* __restrict__ bias,
                                                        ushort_t* __restrict__ tbf,
                                                        ushort_t* __restrict__ ubf) {
    __shared__ int hist[BUKSZ];
    __shared__ int cur[BUKSZ];
    __shared__ ushort_t stage[PAD2];
    int b = blockIdx.x, tid = threadIdx.x;
    if (b < NBUK) {
        int base = b * PAD2;
        int count = cursor[b] - base;
        int node_base = b << BSHIFT;
        if (tid < BUKSZ) hist[tid] = 0;
        __syncthreads();
        for (int i = tid; i < count; i += 512)
            atomicAdd(&hist[tmp[base + i] >> 16], 1);
        __syncthreads();
        int v = (tid < BUKSZ) ? hist[tid] : 0;
        int vr = (v + 15) & ~15;               // 16-aligned per-node segment (clamp-free agg)
        __syncthreads();
        if (tid < BUKSZ) hist[tid] = vr;
#pragma unroll
        for (int o = 1; o < BUKSZ; o <<= 1) {  // Hillis-Steele inclusive scan
            __syncthreads();
            int y = (tid >= o && tid < BUKSZ) ? hist[tid - o] : 0;
            __syncthreads();
            if (tid < BUKSZ) hist[tid] += y;
        }
        __syncthreads();
        int excl = 0;
        if (tid < BUKSZ) {
            excl = hist[tid] - vr;
            cur[tid] = excl;
            int node = node_base + tid;
            if (node < N_NODES) row_info[node] = make_int2(base + excl, v);
        }
        __syncthreads();
        if (tid < BUKSZ) {                     // pad slots -> zero-row index
            for (int p = v; p < vr; ++p) stage[excl + p] = (ushort_t)N_NODES;
        }
        for (int i = tid; i < count; i += 512) {
            int p = tmp[base + i];
            int slot = atomicAdd(&cur[p >> 16], 1);
            stage[slot] = (ushort_t)(p & 0xFFFF);
        }
        __syncthreads();
        int total = hist[BUKSZ - 1];
        for (int i = tid; i < total; i += 512)
            csr[base + i] = stage[i];
    } else {
        // gemm1: t1 = x@Wrel (f16), u1 = x@Wroot + b1 (f16)
        int lane = tid & 63;
        float wn[64], ws[64];
#pragma unroll
        for (int k = 0; k < 64; ++k) {
            wn[k] = Wrel[k * 64 + lane];
            ws[k] = Wroot[k * 64 + lane];
        }
        float bv = bias[lane];
        int wave = (b - NBUK) * 8 + (tid >> 6);
        int nwaves = (gridDim.x - NBUK) * 8;
        if (wave == 0) tbf[(size_t)N_NODES * 64 + lane] = 0;   // zero clamp row (128B)
        for (int i = wave; i < N_NODES; i += nwaves) {
            float hv = x[i * 64 + lane];
            float tacc = 0.f, uacc = bv;
#pragma unroll
            for (int k = 0; k < 64; ++k) {
                float hk = bcastf(hv, k);
                tacc = fmaf(hk, wn[k], tacc);
                uacc = fmaf(hk, ws[k], uacc);
            }
            tbf[(size_t)i * 64 + lane] = f2h(tacc);
            ubf[(size_t)i * 64 + lane] = f2h(uacc);
        }
    }
}

// ---------------- wide-gather aggregate: 16B/lane, 2 gathers + 1 idx per 16 edges ----------------
// lane: e = lane>>3 (edge slot 0..7), c = lane&7 (channel octet: ch 8c..8c+7)
// edge pair (2e, 2e+1) of each 16-edge chunk handled by lanes with this e.
// After loop: 3-stage f16 xor-reduce over e-bits (8,16,32); all lanes hold their octet sum.
__device__ __forceinline__ void agg8(const ushort_t* __restrict__ tbf,
                                     const ushort_t* __restrict__ csr,
                                     int start, int deg, int e, int c,
                                     unsigned iv0, float f[8]) {
    const ushort_t* cp = csr + start;          // start is 16-aligned
    hf2 a0{0,0}, a1{0,0}, a2{0,0}, a3{0,0};
    hf2 b0{0,0}, b1{0,0}, b2{0,0}, b3{0,0};
    int vr = (deg + 15) & ~15;
    unsigned iv = iv0;
    for (int base = 0; base < vr; base += 16) {
        int sA = (int)(iv & 0xFFFF);
        int sB = (int)(iv >> 16);
        const uint4 wA = *(const uint4*)(tbf + (size_t)sA * 64 + c * 8);
        const uint4 wB = *(const uint4*)(tbf + (size_t)sB * 64 + c * 8);
        int nb = base + 16;
        iv = *(const unsigned*)(cp + ((nb < vr) ? nb : 0) + 2 * e);  // prefetch next idx
        a0 += u2h(wA.x); a1 += u2h(wA.y); a2 += u2h(wA.z); a3 += u2h(wA.w);
        b0 += u2h(wB.x); b1 += u2h(wB.y); b2 += u2h(wB.z); b3 += u2h(wB.w);
    }
    hf2 s0 = a0 + b0, s1 = a1 + b1, s2 = a2 + b2, s3 = a3 + b3;
    s0 = sxor(s0, 8);  s1 = sxor(s1, 8);  s2 = sxor(s2, 8);  s3 = sxor(s3, 8);
    s0 = sxor(s0, 16); s1 = sxor(s1, 16); s2 = sxor(s2, 16); s3 = sxor(s3, 16);
    s0 = sxor(s0, 32); s1 = sxor(s1, 32); s2 = sxor(s2, 32); s3 = sxor(s3, 32);
    f[0] = (float)s0.x; f[1] = (float)s0.y; f[2] = (float)s1.x; f[3] = (float)s1.y;
    f[4] = (float)s2.x; f[5] = (float)s2.y; f[6] = (float)s3.x; f[7] = (float)s3.y;
}

// ---------------- fused: agg(layer k) [+ dout] + dot2-gemm(layer k+1) ----------------
__global__ __launch_bounds__(256, 6) void fused_kernel(const ushort_t* __restrict__ tin,
                                                       const ushort_t* __restrict__ uin,
                                                       const int2* __restrict__ row_info,
                                                       const ushort_t* __restrict__ csr,
                                                       const uint4* __restrict__ pwL,
                                                       const float* __restrict__ bias_next,
                                                       ushort_t* __restrict__ tout,
                                                       ushort_t* __restrict__ uout,
                                                       float* __restrict__ dout,
                                                       int use_mean) {
    __shared__ uint4 wlds[1024];   // [kp*16+q] Wn, +512 Ws; f16 pairs; linear (0 conflicts)
    __shared__ float blds[64];
    int tid = threadIdx.x;
    for (int i = tid; i < 1024; i += 256) wlds[i] = pwL[i];
    if (tid < 64) blds[tid] = bias_next[tid];
    if (blockIdx.x == 0 && tid < 32)       // zero clamp row of tout (128B)
        ((unsigned*)(tout + (size_t)N_NODES * 64))[tid] = 0;
    __syncthreads();
    int lane = tid & 63;
    int g = lane >> 4, q = lane & 15;      // gemm roles
    int e = lane >> 3, c = lane & 7;       // agg roles
    int w = blockIdx.x * 4 + (tid >> 6);

    // hoist: all NPW nodes' row_info, first idx word, and u rows (independent loads)
    int2 ri[NPW];
    unsigned iv0[NPW];
    uint4 uvp[NPW];
#pragma unroll
    for (int i = 0; i < NPW; ++i) ri[i] = row_info[w + FWAVES * i];     // 4*12500=50000 exact
#pragma unroll
    for (int i = 0; i < NPW; ++i) iv0[i] = *(const unsigned*)(csr + ri[i].x + 2 * e);
#pragma unroll
    for (int i = 0; i < NPW; ++i)
        uvp[i] = *(const uint4*)(uin + (size_t)(w + FWAVES * i) * 64 + c * 8);

#pragma unroll
    for (int i = 0; i < NPW; ++i) {
        int node = w + FWAVES * i;
        float f[8];
        agg8(tin, csr, ri[i].x, ri[i].y, e, c, iv0[i], f);
        float sc = use_mean ? 1.f / fmaxf((float)ri[i].y, 1.f) : 1.f;
        hf2 ua = u2h(uvp[i].x), ub = u2h(uvp[i].y), uc = u2h(uvp[i].z), ud = u2h(uvp[i].w);
        float h0 = fmaxf((float)ua.x + f[0] * sc, 0.f);
        float h1 = fmaxf((float)ua.y + f[1] * sc, 0.f);
        float h2 = fmaxf((float)ub.x + f[2] * sc, 0.f);
        float h3 = fmaxf((float)ub.y + f[3] * sc, 0.f);
        float h4 = fmaxf((float)uc.x + f[4] * sc, 0.f);
        float h5 = fmaxf((float)uc.y + f[5] * sc, 0.f);
        float h6 = fmaxf((float)ud.x + f[6] * sc, 0.f);
        float h7 = fmaxf((float)ud.y + f[7] * sc, 0.f);
        if (dout && lane < 8) {            // 8 lanes x 32B = full 256B row
            *(float4*)(dout + (size_t)node * 64 + c * 8)     = make_float4(h0, h1, h2, h3);
            *(float4*)(dout + (size_t)node * 64 + c * 8 + 4) = make_float4(h4, h5, h6, h7);
        }
        // pack h into f16 k-pairs: lane c holds kp = 4c..4c+3
        unsigned hp0 = pkh(h0, h1), hp1 = pkh(h2, h3), hp2 = pkh(h4, h5), hp3 = pkh(h6, h7);
        // dot2 gemm: group g covers kp in [8g, 8g+8); pair kp lives in lane kp>>2, reg kp&3
        float4 tp{0,0,0,0}, up{0,0,0,0};
#pragma unroll
        for (int jp = 0; jp < 8; ++jp) {
            int kp = 8 * g + jp;
            const uint4 wvn = wlds[kp * 16 + q];
            const uint4 wvs = wlds[512 + kp * 16 + q];
            int srcl = 2 * g + (jp >> 2);
            unsigned hsel = (jp & 3) == 0 ? hp0 : (jp & 3) == 1 ? hp1 : (jp & 3) == 2 ? hp2 : hp3;
            unsigned hu = (unsigned)__shfl((int)hsel, srcl);
            hf2 hh = u2h(hu);
            tp.x = __builtin_amdgcn_fdot2(hh, u2h(wvn.x), tp.x, false);
            tp.y = __builtin_amdgcn_fdot2(hh, u2h(wvn.y), tp.y, false);
            tp.z = __builtin_amdgcn_fdot2(hh, u2h(wvn.z), tp.z, false);
            tp.w = __builtin_amdgcn_fdot2(hh, u2h(wvn.w), tp.w, false);
            up.x = __builtin_amdgcn_fdot2(hh, u2h(wvs.x), up.x, false);
            up.y = __builtin_amdgcn_fdot2(hh, u2h(wvs.y), up.y, false);
            up.z = __builtin_amdgcn_fdot2(hh, u2h(wvs.z), up.z, false);
            up.w = __builtin_amdgcn_fdot2(hh, u2h(wvs.w), up.w, false);
        }
        bfly(tp); bfly(up);
        if (g == 0) {
            const float4 bv = *(const float4*)&blds[q * 4];
            uint2 upk, tpk;
            upk.x = pkh(up.x + bv.x, up.y + bv.y);
            upk.y = pkh(up.z + bv.z, up.w + bv.w);
            tpk.x = pkh(tp.x, tp.y);
            tpk.y = pkh(tp.z, tp.w);
            *(uint2*)(uout + (size_t)node * 64 + q * 4) = upk;
            *(uint2*)(tout + (size_t)node * 64 + q * 4) = tpk;
        }
    }
}

// ---------------- final agg-only ----------------
__global__ __launch_bounds__(256, 8) void agg_kernel(const ushort_t* __restrict__ tbf,
                                                     const ushort_t* __restrict__ ubf,
                                                     const int2* __restrict__ row_info,
                                                     const ushort_t* __restrict__ csr,
                                                     float* __restrict__ out, int use_mean) {
    int lane = threadIdx.x & 63;
    int e = lane >> 3, c = lane & 7;
    int node = (blockIdx.x * 256 + threadIdx.x) >> 6;
    if (node >= N_NODES) return;
    int2 ri = row_info[node];
    unsigned iv0 = *(const unsigned*)(csr + ri.x + 2 * e);
    uint4 uv4 = *(const uint4*)(ubf + (size_t)node * 64 + c * 8);
    float f[8];
    agg8(tbf, csr, ri.x, ri.y, e, c, iv0, f);
    float sc = use_mean ? 1.f / fmaxf((float)ri.y, 1.f) : 1.f;
    if (lane < 8) {
        hf2 ua = u2h(uv4.x), ub = u2h(uv4.y), uc = u2h(uv4.z), ud = u2h(uv4.w);
        float4 r0, r1;
        r0.x = fmaxf((float)ua.x + f[0] * sc, 0.f);
        r0.y = fmaxf((float)ua.y + f[1] * sc, 0.f);
        r0.z = fmaxf((float)ub.x + f[2] * sc, 0.f);
        r0.w = fmaxf((float)ub.y + f[3] * sc, 0.f);
        r1.x = fmaxf((float)uc.x + f[4] * sc, 0.f);
        r1.y = fmaxf((float)uc.y + f[5] * sc, 0.f);
        r1.z = fmaxf((float)ud.x + f[6] * sc, 0.f);
        r1.w = fmaxf((float)ud.y + f[7] * sc, 0.f);
        *(float4*)(out + (size_t)node * 64 + c * 8)     = r0;
        *(float4*)(out + (size_t)node * 64 + c * 8 + 4) = r1;
    }
}

// ---------------- launch: 7 dispatches ----------------
extern "C" void kernel_launch(void* const* d_in, const int* in_sizes, int n_in,
                              void* d_out, int out_size, void* d_ws, size_t ws_size,
                              hipStream_t stream) {
    const float* x      = (const float*)d_in[0];
    const int*   ei     = (const int*)d_in[1];
    const float* Wrel1  = (const float*)d_in[2];
    const float* Wroot1 = (const float*)d_in[3];
    const float* b1     = (const float*)d_in[4];
    const float* Wself2 = (const float*)d_in[5];
    const float* Wnbr2  = (const float*)d_in[6];
    const float* b2     = (const float*)d_in[7];
    const float* Wself3 = (const float*)d_in[8];
    const float* Wnbr3  = (const float*)d_in[9];
    const float* b3     = (const float*)d_in[10];
    const float* Wself4 = (const float*)d_in[11];
    const float* Wnbr4  = (const float*)d_in[12];
    const float* b4     = (const float*)d_in[13];

    const int N = N_NODES, E = N_EDGES;

    auto align = [](size_t o) { return (o + 255) & ~(size_t)255; };
    char* base = (char*)d_ws;
    size_t off = 0;
    int*  cursor   = (int*)(base + off);  off = align(off + (size_t)NBUK * 4);
    int2* row_info = (int2*)(base + off); off = align(off + (size_t)N * 8);
    int*  tmp      = (int*)(base + off);  off = align(off + (size_t)NBUK * PAD2 * 4);
    ushort_t* csr  = (ushort_t*)(base + off); off = align(off + (size_t)NBUK * PAD2 * 2 + 1024);
    uint4* pw      = (uint4*)(base + off);    off = align(off + (size_t)3 * 1024 * 16);
    ushort_t* tbA  = (ushort_t*)(base + off); off = align(off + (size_t)(N + 1) * 64 * 2);
    ushort_t* tbB  = (ushort_t*)(base + off); off = align(off + (size_t)(N + 1) * 64 * 2);
    ushort_t* ubA  = (ushort_t*)(base + off); off = align(off + (size_t)N * 64 * 2);
    ushort_t* ubB  = (ushort_t*)(base + off); off = align(off + (size_t)N * 64 * 2);

    float* out1 = (float*)d_out;
    float* out2 = (float*)d_out + (size_t)N * 64;

    // 1) cursor init + W f16 packing
    init_kernel<<<4, 512, 0, stream>>>(cursor, Wnbr2, Wself2, Wnbr3, Wself3, Wnbr4, Wself4, pw);
    // 2) bucket scatter
    scatter_fused_kernel<<<GBIN, 256, 0, stream>>>(ei, cursor, tmp, E);
    // 3) per-bucket counting sort (16-aligned, zero-row pads) || gemm1 -> t1(tbA), u1(ubA)
    bucketize_kernel<<<NBUK + 1024, 512, 0, stream>>>(tmp, cursor, row_info, csr,
                                                      x, Wrel1, Wroot1, b1, tbA, ubA);
    // 4) F1: agg1(mean) + gemm2 -> t2(tbB), u2(ubB)
    fused_kernel<<<FBLK, 256, 0, stream>>>(tbA, ubA, row_info, csr, pw,        b2, tbB, ubB, nullptr, 1);
    // 5) F2: agg2 -> out1, + gemm3 -> t3(tbA), u3(ubA)
    fused_kernel<<<FBLK, 256, 0, stream>>>(tbB, ubB, row_info, csr, pw + 1024, b3, tbA, ubA, out1, 0);
    // 6) F3: agg3 + gemm4 -> t4(tbB), u4(ubB)
    fused_kernel<<<FBLK, 256, 0, stream>>>(tbA, ubA, row_info, csr, pw + 2048, b4, tbB, ubB, nullptr, 0);
    // 7) F4: agg4 -> out2
    agg_kernel<<<(N + 3) / 4, 256, 0, stream>>>(tbB, ubB, row_info, csr, out2, 0);
}

// Round 5
// 316.608 us; speedup vs baseline: 1.8230x; 1.8230x over previous
//
#include <hip/hip_runtime.h>
#include <hip/hip_fp16.h>

#define N_NODES 50000
#define HIDDEN  64
#define N_EDGES 1200000

#define BSHIFT 7                       // 128 nodes per bucket
#define BUKSZ  128
#define NBUK   391                     // ceil(50000/128)
#define GBIN   512                     // scatter blocks (2 blocks/CU)
#define PAD2   6144                    // csr capacity per bucket (avg 3072 + 16-align pads)
#define FWAVES 12500                   // fused-layer waves
#define FBLK   (FWAVES / 4)
#define NPW    4

typedef unsigned short ushort_t;
typedef _Float16 hf2 __attribute__((ext_vector_type(2)));
typedef float nf4 __attribute__((ext_vector_type(4)));   // native vec for NT stores

__device__ __forceinline__ float bcastf(float v, int k) {
    return __int_as_float(__builtin_amdgcn_readlane(__float_as_int(v), k));
}
__device__ __forceinline__ hf2 u2h(unsigned u) { union { unsigned u; hf2 h; } x; x.u = u; return x.h; }
__device__ __forceinline__ unsigned h2u(hf2 h) { union { hf2 h; unsigned u; } x; x.h = h; return x.u; }
__device__ __forceinline__ unsigned pkh(float a, float b) {   // 2xf32 -> packed f16 (v_cvt_pkrtz)
    __half2 h = __float22half2_rn(make_float2(a, b));
    union { __half2 h; unsigned u; } x; x.h = h; return x.u;
}
__device__ __forceinline__ ushort_t f2h(float a) {
    __half h = __float2half_rn(a);
    union { __half h; ushort_t u; } x; x.h = h; return x.u;
}
__device__ __forceinline__ void ntst4(float* p, float a, float b, float c, float d) {
    nf4 v; v.x = a; v.y = b; v.z = c; v.w = d;
    __builtin_nontemporal_store(v, (nf4*)p);
}
__device__ __forceinline__ void bfly(float4& a) {      // all lanes end with group-sum (xor16,32)
    a.x += __shfl_xor(a.x, 16); a.y += __shfl_xor(a.y, 16);
    a.z += __shfl_xor(a.z, 16); a.w += __shfl_xor(a.w, 16);
    a.x += __shfl_xor(a.x, 32); a.y += __shfl_xor(a.y, 32);
    a.z += __shfl_xor(a.z, 32); a.w += __shfl_xor(a.w, 32);
}

// ---------------- 1) init: cursor + W f16-pair packing ----------------
__global__ __launch_bounds__(512) void init_kernel(int* __restrict__ cursor,
                                                   const float* __restrict__ Wn2, const float* __restrict__ Ws2,
                                                   const float* __restrict__ Wn3, const float* __restrict__ Ws3,
                                                   const float* __restrict__ Wn4, const float* __restrict__ Ws4,
                                                   uint4* __restrict__ pw) {
    int b = blockIdx.x, tid = threadIdx.x;
    if (b == 0) {
        if (tid < NBUK) cursor[tid] = tid * PAD2;
    } else {
        int layer = b - 1;
        const float* Wn = (layer == 0) ? Wn2 : (layer == 1) ? Wn3 : Wn4;
        const float* Ws = (layer == 0) ? Ws2 : (layer == 1) ? Ws3 : Ws4;
        int kp = tid >> 4, q = tid & 15;           // tid < 512
        {
            const float4 a = *(const float4*)(Wn + (2 * kp) * 64 + 4 * q);
            const float4 c = *(const float4*)(Wn + (2 * kp + 1) * 64 + 4 * q);
            pw[layer * 1024 + tid] = make_uint4(pkh(a.x, c.x), pkh(a.y, c.y), pkh(a.z, c.z), pkh(a.w, c.w));
        }
        {
            const float4 a = *(const float4*)(Ws + (2 * kp) * 64 + 4 * q);
            const float4 c = *(const float4*)(Ws + (2 * kp + 1) * 64 + 4 * q);
            pw[layer * 1024 + 512 + tid] = make_uint4(pkh(a.x, c.x), pkh(a.y, c.y), pkh(a.z, c.z), pkh(a.w, c.w));
        }
    }
}

// ---------------- 2) scatter (R8-proven) ----------------
__global__ __launch_bounds__(256) void scatter_fused_kernel(const int* __restrict__ ei,
                                                            int* __restrict__ cursor,
                                                            int* __restrict__ tmp, int E) {
    __shared__ int h[NBUK];
    __shared__ int cur[NBUK];
    int tid = threadIdx.x;
    for (int b = tid; b < NBUK; b += 256) h[b] = 0;
    __syncthreads();
    for (int e = blockIdx.x * 256 + tid; e < E; e += GBIN * 256)
        atomicAdd(&h[ei[E + e] >> BSHIFT], 1);
    __syncthreads();
    for (int b = tid; b < NBUK; b += 256) cur[b] = atomicAdd(&cursor[b], h[b]);
    __syncthreads();
    for (int e = blockIdx.x * 256 + tid; e < E; e += GBIN * 256) {
        int src = ei[e];
        int dst = ei[E + e];
        int p = atomicAdd(&cur[dst >> BSHIFT], 1);
        tmp[p] = src | ((dst & (BUKSZ - 1)) << 16);
    }
}

// ---------------- 3) bucketize (16-aligned, pad=50000) || gemm1 ----------------
__global__ __launch_bounds__(512) void bucketize_kernel(const int* __restrict__ tmp,
                                                        const int* __restrict__ cursor,
                                                        int2* __restrict__ row_info,
                                                        ushort_t* __restrict__ csr,
                                                        const float* __restrict__ x,
                                                        const float* __restrict__ Wrel,
                                                        const float* __restrict__ Wroot,
                                                        const float* __restrict__ bias,
                                                        ushort_t* __restrict__ tbf,
                                                        ushort_t* __restrict__ ubf) {
    __shared__ int hist[BUKSZ];
    __shared__ int cur[BUKSZ];
    __shared__ ushort_t stage[PAD2];
    int b = blockIdx.x, tid = threadIdx.x;
    if (b < NBUK) {
        int base = b * PAD2;
        int count = cursor[b] - base;
        int node_base = b << BSHIFT;
        if (tid < BUKSZ) hist[tid] = 0;
        __syncthreads();
        for (int i = tid; i < count; i += 512)
            atomicAdd(&hist[tmp[base + i] >> 16], 1);
        __syncthreads();
        int v = (tid < BUKSZ) ? hist[tid] : 0;
        int vr = (v + 15) & ~15;               // 16-aligned per-node segment (clamp-free agg)
        __syncthreads();
        if (tid < BUKSZ) hist[tid] = vr;
#pragma unroll
        for (int o = 1; o < BUKSZ; o <<= 1) {  // Hillis-Steele inclusive scan
            __syncthreads();
            int y = (tid >= o && tid < BUKSZ) ? hist[tid - o] : 0;
            __syncthreads();
            if (tid < BUKSZ) hist[tid] += y;
        }
        __syncthreads();
        int excl = 0;
        if (tid < BUKSZ) {
            excl = hist[tid] - vr;
            cur[tid] = excl;
            int node = node_base + tid;
            if (node < N_NODES) row_info[node] = make_int2(base + excl, v);
        }
        __syncthreads();
        if (tid < BUKSZ) {                     // pad slots -> zero-row index
            for (int p = v; p < vr; ++p) stage[excl + p] = (ushort_t)N_NODES;
        }
        for (int i = tid; i < count; i += 512) {
            int p = tmp[base + i];
            int slot = atomicAdd(&cur[p >> 16], 1);
            stage[slot] = (ushort_t)(p & 0xFFFF);
        }
        __syncthreads();
        int total = hist[BUKSZ - 1];
        for (int i = tid; i < total; i += 512)
            csr[base + i] = stage[i];
    } else {
        // gemm1: t1 = x@Wrel (f16), u1 = x@Wroot + b1 (f16)
        int lane = tid & 63;
        float wn[64], ws[64];
#pragma unroll
        for (int k = 0; k < 64; ++k) {
            wn[k] = Wrel[k * 64 + lane];
            ws[k] = Wroot[k * 64 + lane];
        }
        float bv = bias[lane];
        int wave = (b - NBUK) * 8 + (tid >> 6);
        int nwaves = (gridDim.x - NBUK) * 8;
        if (wave == 0) tbf[(size_t)N_NODES * 64 + lane] = 0;   // zero clamp row (128B)
        for (int i = wave; i < N_NODES; i += nwaves) {
            float hv = x[i * 64 + lane];
            float tacc = 0.f, uacc = bv;
#pragma unroll
            for (int k = 0; k < 64; ++k) {
                float hk = bcastf(hv, k);
                tacc = fmaf(hk, wn[k], tacc);
                uacc = fmaf(hk, ws[k], uacc);
            }
            tbf[(size_t)i * 64 + lane] = f2h(tacc);
            ubf[(size_t)i * 64 + lane] = f2h(uacc);
        }
    }
}

// ---------------- clamp-free f16 gather-aggregate, 32-edge pipelined ----------------
// Proven R2 shape: row read as uint2 (8B) by 16 contiguous lanes. 32 edges per
// iteration = 8 gathers + 2 idx loads in flight; wave-uniform 16-edge tail.
__device__ __forceinline__ uint2 ldrow(const ushort_t* __restrict__ tbf, int s, int q) {
    return *(const uint2*)(tbf + (size_t)s * 64 + q * 4);
}

__device__ __forceinline__ float4 agg_core_p(const ushort_t* __restrict__ tbf,
                                             const ushort_t* __restrict__ csr,
                                             int start, int deg, int g, int q,
                                             uint2 iva, uint2 ivb) {
    const ushort_t* cp = csr + start;          // start is 16-aligned
    hf2 l0{0,0}, l1{0,0}, l2{0,0}, l3{0,0};
    hf2 m0{0,0}, m1{0,0}, m2{0,0}, m3{0,0};
    int vr = (deg + 15) & ~15;
    int full = vr & ~31;
    for (int base = 0; base < full; base += 32) {
        int s0 = (int)(iva.x & 0xFFFF);
        int s1 = (int)(iva.x >> 16);
        int s2 = (int)(iva.y & 0xFFFF);
        int s3 = (int)(iva.y >> 16);
        int s4 = (int)(ivb.x & 0xFFFF);
        int s5 = (int)(ivb.x >> 16);
        int s6 = (int)(ivb.y & 0xFFFF);
        int s7 = (int)(ivb.y >> 16);
        const uint2 w0 = ldrow(tbf, s0, q);
        const uint2 w1 = ldrow(tbf, s1, q);
        const uint2 w2 = ldrow(tbf, s2, q);
        const uint2 w3 = ldrow(tbf, s3, q);
        const uint2 w4 = ldrow(tbf, s4, q);
        const uint2 w5 = ldrow(tbf, s5, q);
        const uint2 w6 = ldrow(tbf, s6, q);
        const uint2 w7 = ldrow(tbf, s7, q);
        int nb = base + 32;
        iva = *(const uint2*)(cp + ((nb < vr) ? nb : 0) + 4 * g);
        ivb = *(const uint2*)(cp + ((nb + 16 < vr) ? nb + 16 : 0) + 4 * g);
        l0 += u2h(w0.x); m0 += u2h(w0.y);
        l1 += u2h(w1.x); m1 += u2h(w1.y);
        l2 += u2h(w2.x); m2 += u2h(w2.y);
        l3 += u2h(w3.x); m3 += u2h(w3.y);
        l0 += u2h(w4.x); m0 += u2h(w4.y);
        l1 += u2h(w5.x); m1 += u2h(w5.y);
        l2 += u2h(w6.x); m2 += u2h(w6.y);
        l3 += u2h(w7.x); m3 += u2h(w7.y);
    }
    if (vr & 16) {                             // wave-uniform tail (16 edges) from iva
        int s0 = (int)(iva.x & 0xFFFF);
        int s1 = (int)(iva.x >> 16);
        int s2 = (int)(iva.y & 0xFFFF);
        int s3 = (int)(iva.y >> 16);
        const uint2 w0 = ldrow(tbf, s0, q);
        const uint2 w1 = ldrow(tbf, s1, q);
        const uint2 w2 = ldrow(tbf, s2, q);
        const uint2 w3 = ldrow(tbf, s3, q);
        l0 += u2h(w0.x); m0 += u2h(w0.y);
        l1 += u2h(w1.x); m1 += u2h(w1.y);
        l2 += u2h(w2.x); m2 += u2h(w2.y);
        l3 += u2h(w3.x); m3 += u2h(w3.y);
    }
    hf2 lo = (l0 + l1) + (l2 + l3);
    hf2 hi = (m0 + m1) + (m2 + m3);
    float4 acc = make_float4((float)lo.x, (float)lo.y, (float)hi.x, (float)hi.y);
    bfly(acc);
    return acc;
}

__device__ __forceinline__ float4 unpack_u2(uint2 uv) {
    hf2 a = u2h(uv.x), b = u2h(uv.y);
    return make_float4((float)a.x, (float)a.y, (float)b.x, (float)b.y);
}

// ---------------- fused: agg(layer k) [+ dout] + dot2-gemm(layer k+1) ----------------
__global__ __launch_bounds__(256, 6) void fused_kernel(const ushort_t* __restrict__ tin,
                                                       const ushort_t* __restrict__ uin,
                                                       const int2* __restrict__ row_info,
                                                       const ushort_t* __restrict__ csr,
                                                       const uint4* __restrict__ pwL,
                                                       const float* __restrict__ bias_next,
                                                       ushort_t* __restrict__ tout,
                                                       ushort_t* __restrict__ uout,
                                                       float* __restrict__ dout,
                                                       int use_mean) {
    __shared__ uint4 wlds[1024];   // [kp*16+q] Wn, +512 Ws; f16 pairs; linear (0 conflicts)
    __shared__ float blds[64];
    int tid = threadIdx.x;
    for (int i = tid; i < 1024; i += 256) wlds[i] = pwL[i];
    if (tid < 64) blds[tid] = bias_next[tid];
    if (blockIdx.x == 0 && tid < 32)       // zero clamp row of tout (128B)
        ((unsigned*)(tout + (size_t)N_NODES * 64))[tid] = 0;
    __syncthreads();
    int lane = tid & 63, g = lane >> 4, q = lane & 15;
    int w = blockIdx.x * 4 + (tid >> 6);

    // hoist: all NPW nodes' row_info, first two idx chunks, and u rows (independent loads)
    int2 ri[NPW];
    uint2 iv0[NPW], iv1[NPW];
    uint2 uvp[NPW];
#pragma unroll
    for (int i = 0; i < NPW; ++i) ri[i] = row_info[w + FWAVES * i];     // 4*12500=50000 exact
#pragma unroll
    for (int i = 0; i < NPW; ++i) {
        iv0[i] = *(const uint2*)(csr + ri[i].x + 4 * g);
        int vri = (ri[i].y + 15) & ~15;
        iv1[i] = *(const uint2*)(csr + ri[i].x + ((vri >= 32) ? 16 : 0) + 4 * g);
    }
#pragma unroll
    for (int i = 0; i < NPW; ++i)
        uvp[i] = *(const uint2*)(uin + (size_t)(w + FWAVES * i) * 64 + q * 4);

#pragma unroll
    for (int i = 0; i < NPW; ++i) {
        int node = w + FWAVES * i;
        float4 acc = agg_core_p(tin, csr, ri[i].x, ri[i].y, g, q, iv0[i], iv1[i]);
        float sc = use_mean ? 1.f / fmaxf((float)ri[i].y, 1.f) : 1.f;
        const float4 uv = unpack_u2(uvp[i]);
        float4 h;
        h.x = fmaxf(uv.x + acc.x * sc, 0.f);
        h.y = fmaxf(uv.y + acc.y * sc, 0.f);
        h.z = fmaxf(uv.z + acc.z * sc, 0.f);
        h.w = fmaxf(uv.w + acc.w * sc, 0.f);
        if (dout && g == 0)                // NT: dout never re-read on GPU this iteration
            ntst4(dout + (size_t)node * 64 + q * 4, h.x, h.y, h.z, h.w);
        // pack h into f16 k-pairs: lane q holds kp=2q (h.x,h.y) and kp=2q+1 (h.z,h.w)
        int hp_lo = (int)pkh(h.x, h.y);
        int hp_hi = (int)pkh(h.z, h.w);
        // dot2 gemm: group g covers kp in [8g, 8g+8)
        float4 tp{0,0,0,0}, up{0,0,0,0};
#pragma unroll
        for (int jp = 0; jp < 8; ++jp) {
            int kp = 8 * g + jp;
            const uint4 wvn = wlds[kp * 16 + q];
            const uint4 wvs = wlds[512 + kp * 16 + q];
            int srcl = 4 * g + (jp >> 1);
            unsigned hu = (unsigned)__shfl((jp & 1) ? hp_hi : hp_lo, srcl);
            hf2 hh = u2h(hu);
            tp.x = __builtin_amdgcn_fdot2(hh, u2h(wvn.x), tp.x, false);
            tp.y = __builtin_amdgcn_fdot2(hh, u2h(wvn.y), tp.y, false);
            tp.z = __builtin_amdgcn_fdot2(hh, u2h(wvn.z), tp.z, false);
            tp.w = __builtin_amdgcn_fdot2(hh, u2h(wvn.w), tp.w, false);
            up.x = __builtin_amdgcn_fdot2(hh, u2h(wvs.x), up.x, false);
            up.y = __builtin_amdgcn_fdot2(hh, u2h(wvs.y), up.y, false);
            up.z = __builtin_amdgcn_fdot2(hh, u2h(wvs.z), up.z, false);
            up.w = __builtin_amdgcn_fdot2(hh, u2h(wvs.w), up.w, false);
        }
        bfly(tp); bfly(up);
        if (g == 0) {
            const float4 bv = *(const float4*)&blds[q * 4];
            uint2 upk, tpk;
            upk.x = pkh(up.x + bv.x, up.y + bv.y);
            upk.y = pkh(up.z + bv.z, up.w + bv.w);
            tpk.x = pkh(tp.x, tp.y);
            tpk.y = pkh(tp.z, tp.w);
            *(uint2*)(uout + (size_t)node * 64 + q * 4) = upk;
            *(uint2*)(tout + (size_t)node * 64 + q * 4) = tpk;
        }
    }
}

// ---------------- final agg-only ----------------
__global__ __launch_bounds__(256, 8) void agg_kernel(const ushort_t* __restrict__ tbf,
                                                     const ushort_t* __restrict__ ubf,
                                                     const int2* __restrict__ row_info,
                                                     const ushort_t* __restrict__ csr,
                                                     float* __restrict__ out, int use_mean) {
    int lane = threadIdx.x & 63;
    int g = lane >> 4, q = lane & 15;
    int node = (blockIdx.x * 256 + threadIdx.x) >> 6;
    if (node >= N_NODES) return;
    int2 ri = row_info[node];
    uint2 iv0 = *(const uint2*)(csr + ri.x + 4 * g);
    int vri = (ri.y + 15) & ~15;
    uint2 iv1 = *(const uint2*)(csr + ri.x + ((vri >= 32) ? 16 : 0) + 4 * g);
    float4 acc = agg_core_p(tbf, csr, ri.x, ri.y, g, q, iv0, iv1);
    float scale = use_mean ? 1.f / fmaxf((float)ri.y, 1.f) : 1.f;
    if (g == 0) {
        const uint2 uvr = *(const uint2*)(ubf + (size_t)node * 64 + q * 4);
        const float4 uv = unpack_u2(uvr);
        float rx = fmaxf(uv.x + acc.x * scale, 0.f);
        float ry = fmaxf(uv.y + acc.y * scale, 0.f);
        float rz = fmaxf(uv.z + acc.z * scale, 0.f);
        float rw = fmaxf(uv.w + acc.w * scale, 0.f);
        ntst4(out + (size_t)node * 64 + q * 4, rx, ry, rz, rw);
    }
}

// ---------------- launch: 7 dispatches ----------------
extern "C" void kernel_launch(void* const* d_in, const int* in_sizes, int n_in,
                              void* d_out, int out_size, void* d_ws, size_t ws_size,
                              hipStream_t stream) {
    const float* x      = (const float*)d_in[0];
    const int*   ei     = (const int*)d_in[1];
    const float* Wrel1  = (const float*)d_in[2];
    const float* Wroot1 = (const float*)d_in[3];
    const float* b1     = (const float*)d_in[4];
    const float* Wself2 = (const float*)d_in[5];
    const float* Wnbr2  = (const float*)d_in[6];
    const float* b2     = (const float*)d_in[7];
    const float* Wself3 = (const float*)d_in[8];
    const float* Wnbr3  = (const float*)d_in[9];
    const float* b3     = (const float*)d_in[10];
    const float* Wself4 = (const float*)d_in[11];
    const float* Wnbr4  = (const float*)d_in[12];
    const float* b4     = (const float*)d_in[13];

    const int N = N_NODES, E = N_EDGES;

    auto align = [](size_t o) { return (o + 255) & ~(size_t)255; };
    char* base = (char*)d_ws;
    size_t off = 0;
    int*  cursor   = (int*)(base + off);  off = align(off + (size_t)NBUK * 4);
    int2* row_info = (int2*)(base + off); off = align(off + (size_t)N * 8);
    int*  tmp      = (int*)(base + off);  off = align(off + (size_t)NBUK * PAD2 * 4);
    ushort_t* csr  = (ushort_t*)(base + off); off = align(off + (size_t)NBUK * PAD2 * 2 + 1024);
    uint4* pw      = (uint4*)(base + off);    off = align(off + (size_t)3 * 1024 * 16);
    ushort_t* tbA  = (ushort_t*)(base + off); off = align(off + (size_t)(N + 1) * 64 * 2);
    ushort_t* tbB  = (ushort_t*)(base + off); off = align(off + (size_t)(N + 1) * 64 * 2);
    ushort_t* ubA  = (ushort_t*)(base + off); off = align(off + (size_t)N * 64 * 2);
    ushort_t* ubB  = (ushort_t*)(base + off); off = align(off + (size_t)N * 64 * 2);

    float* out1 = (float*)d_out;
    float* out2 = (float*)d_out + (size_t)N * 64;

    // 1) cursor init + W f16 packing
    init_kernel<<<4, 512, 0, stream>>>(cursor, Wnbr2, Wself2, Wnbr3, Wself3, Wnbr4, Wself4, pw);
    // 2) bucket scatter
    scatter_fused_kernel<<<GBIN, 256, 0, stream>>>(ei, cursor, tmp, E);
    // 3) per-bucket counting sort (16-aligned, zero-row pads) || gemm1 -> t1(tbA), u1(ubA)
    bucketize_kernel<<<NBUK + 1024, 512, 0, stream>>>(tmp, cursor, row_info, csr,
                                                      x, Wrel1, Wroot1, b1, tbA, ubA);
    // 4) F1: agg1(mean) + gemm2 -> t2(tbB), u2(ubB)
    fused_kernel<<<FBLK, 256, 0, stream>>>(tbA, ubA, row_info, csr, pw,        b2, tbB, ubB, nullptr, 1);
    // 5) F2: agg2 -> out1, + gemm3 -> t3(tbA), u3(ubA)
    fused_kernel<<<FBLK, 256, 0, stream>>>(tbB, ubB, row_info, csr, pw + 1024, b3, tbA, ubA, out1, 0);
    // 6) F3: agg3 + gemm4 -> t4(tbB), u4(ubB)
    fused_kernel<<<FBLK, 256, 0, stream>>>(tbA, ubA, row_info, csr, pw + 2048, b4, tbB, ubB, nullptr, 0);
    // 7) F4: agg4 -> out2
    agg_kernel<<<(N + 3) / 4, 256, 0, stream>>>(tbB, ubB, row_info, csr, out2, 0);
}

// Round 6
// 269.083 us; speedup vs baseline: 2.1450x; 1.1766x over previous
//
#include <hip/hip_runtime.h>
#include <hip/hip_fp16.h>

#define N_NODES 50000
#define HIDDEN  64
#define N_EDGES 1200000

#define BSHIFT 7                       // 128 nodes per bucket
#define BUKSZ  128
#define NBUK   391                     // ceil(50000/128)
#define GBIN   512                     // scatter blocks (2 blocks/CU)
#define PAD2   6144                    // csr capacity per bucket (avg 3072 + 16-align pads)
#define FWAVES 25000                   // fused-layer waves (NPW=2 nodes each)
#define FBLK   (FWAVES / 4)            // 6250 blocks
#define NPW    2

typedef unsigned short ushort_t;
typedef _Float16 hf2 __attribute__((ext_vector_type(2)));
typedef float nf4 __attribute__((ext_vector_type(4)));   // native vec for NT stores

__device__ __forceinline__ float bcastf(float v, int k) {
    return __int_as_float(__builtin_amdgcn_readlane(__float_as_int(v), k));
}
__device__ __forceinline__ hf2 u2h(unsigned u) { union { unsigned u; hf2 h; } x; x.u = u; return x.h; }
__device__ __forceinline__ unsigned h2u(hf2 h) { union { hf2 h; unsigned u; } x; x.h = h; return x.u; }
__device__ __forceinline__ unsigned pkh(float a, float b) {   // 2xf32 -> packed f16 (v_cvt_pkrtz)
    __half2 h = __float22half2_rn(make_float2(a, b));
    union { __half2 h; unsigned u; } x; x.h = h; return x.u;
}
__device__ __forceinline__ ushort_t f2h(float a) {
    __half h = __float2half_rn(a);
    union { __half h; ushort_t u; } x; x.h = h; return x.u;
}
__device__ __forceinline__ void ntst4(float* p, float a, float b, float c, float d) {
    nf4 v; v.x = a; v.y = b; v.z = c; v.w = d;
    __builtin_nontemporal_store(v, (nf4*)p);
}
__device__ __forceinline__ void bfly(float4& a) {      // all lanes end with group-sum (xor16,32)
    a.x += __shfl_xor(a.x, 16); a.y += __shfl_xor(a.y, 16);
    a.z += __shfl_xor(a.z, 16); a.w += __shfl_xor(a.w, 16);
    a.x += __shfl_xor(a.x, 32); a.y += __shfl_xor(a.y, 32);
    a.z += __shfl_xor(a.z, 32); a.w += __shfl_xor(a.w, 32);
}

// ---------------- 1) init: cursor + W f16-pair packing ----------------
__global__ __launch_bounds__(512) void init_kernel(int* __restrict__ cursor,
                                                   const float* __restrict__ Wn2, const float* __restrict__ Ws2,
                                                   const float* __restrict__ Wn3, const float* __restrict__ Ws3,
                                                   const float* __restrict__ Wn4, const float* __restrict__ Ws4,
                                                   uint4* __restrict__ pw) {
    int b = blockIdx.x, tid = threadIdx.x;
    if (b == 0) {
        if (tid < NBUK) cursor[tid] = tid * PAD2;
    } else {
        int layer = b - 1;
        const float* Wn = (layer == 0) ? Wn2 : (layer == 1) ? Wn3 : Wn4;
        const float* Ws = (layer == 0) ? Ws2 : (layer == 1) ? Ws3 : Ws4;
        int kp = tid >> 4, q = tid & 15;           // tid < 512
        {
            const float4 a = *(const float4*)(Wn + (2 * kp) * 64 + 4 * q);
            const float4 c = *(const float4*)(Wn + (2 * kp + 1) * 64 + 4 * q);
            pw[layer * 1024 + tid] = make_uint4(pkh(a.x, c.x), pkh(a.y, c.y), pkh(a.z, c.z), pkh(a.w, c.w));
        }
        {
            const float4 a = *(const float4*)(Ws + (2 * kp) * 64 + 4 * q);
            const float4 c = *(const float4*)(Ws + (2 * kp + 1) * 64 + 4 * q);
            pw[layer * 1024 + 512 + tid] = make_uint4(pkh(a.x, c.x), pkh(a.y, c.y), pkh(a.z, c.z), pkh(a.w, c.w));
        }
    }
}

// ---------------- 2) scatter (R8-proven) ----------------
__global__ __launch_bounds__(256) void scatter_fused_kernel(const int* __restrict__ ei,
                                                            int* __restrict__ cursor,
                                                            int* __restrict__ tmp, int E) {
    __shared__ int h[NBUK];
    __shared__ int cur[NBUK];
    int tid = threadIdx.x;
    for (int b = tid; b < NBUK; b += 256) h[b] = 0;
    __syncthreads();
    for (int e = blockIdx.x * 256 + tid; e < E; e += GBIN * 256)
        atomicAdd(&h[ei[E + e] >> BSHIFT], 1);
    __syncthreads();
    for (int b = tid; b < NBUK; b += 256) cur[b] = atomicAdd(&cursor[b], h[b]);
    __syncthreads();
    for (int e = blockIdx.x * 256 + tid; e < E; e += GBIN * 256) {
        int src = ei[e];
        int dst = ei[E + e];
        int p = atomicAdd(&cur[dst >> BSHIFT], 1);
        tmp[p] = src | ((dst & (BUKSZ - 1)) << 16);
    }
}

// ---------------- 3) bucketize (16-aligned, pad=50000) || gemm1 ----------------
__global__ __launch_bounds__(512) void bucketize_kernel(const int* __restrict__ tmp,
                                                        const int* __restrict__ cursor,
                                                        int2* __restrict__ row_info,
                                                        ushort_t* __restrict__ csr,
                                                        const float* __restrict__ x,
                                                        const float* __restrict__ Wrel,
                                                        const float* __restrict__ Wroot,
                                                        const float* __restrict__ bias,
                                                        ushort_t* __restrict__ tbf,
                                                        ushort_t* __restrict__ ubf) {
    __shared__ int hist[BUKSZ];
    __shared__ int cur[BUKSZ];
    __shared__ ushort_t stage[PAD2];
    int b = blockIdx.x, tid = threadIdx.x;
    if (b < NBUK) {
        int base = b * PAD2;
        int count = cursor[b] - base;
        int node_base = b << BSHIFT;
        if (tid < BUKSZ) hist[tid] = 0;
        __syncthreads();
        for (int i = tid; i < count; i += 512)
            atomicAdd(&hist[tmp[base + i] >> 16], 1);
        __syncthreads();
        int v = (tid < BUKSZ) ? hist[tid] : 0;
        int vr = (v + 15) & ~15;               // 16-aligned per-node segment (clamp-free agg)
        __syncthreads();
        if (tid < BUKSZ) hist[tid] = vr;
#pragma unroll
        for (int o = 1; o < BUKSZ; o <<= 1) {  // Hillis-Steele inclusive scan
            __syncthreads();
            int y = (tid >= o && tid < BUKSZ) ? hist[tid - o] : 0;
            __syncthreads();
            if (tid < BUKSZ) hist[tid] += y;
        }
        __syncthreads();
        int excl = 0;
        if (tid < BUKSZ) {
            excl = hist[tid] - vr;
            cur[tid] = excl;
            int node = node_base + tid;
            if (node < N_NODES) row_info[node] = make_int2(base + excl, v);
        }
        __syncthreads();
        if (tid < BUKSZ) {                     // pad slots -> zero-row index
            for (int p = v; p < vr; ++p) stage[excl + p] = (ushort_t)N_NODES;
        }
        for (int i = tid; i < count; i += 512) {
            int p = tmp[base + i];
            int slot = atomicAdd(&cur[p >> 16], 1);
            stage[slot] = (ushort_t)(p & 0xFFFF);
        }
        __syncthreads();
        int total = hist[BUKSZ - 1];
        for (int i = tid; i < total; i += 512)
            csr[base + i] = stage[i];
    } else {
        // gemm1: t1 = x@Wrel (f16), u1 = x@Wroot + b1 (f16)
        int lane = tid & 63;
        float wn[64], ws[64];
#pragma unroll
        for (int k = 0; k < 64; ++k) {
            wn[k] = Wrel[k * 64 + lane];
            ws[k] = Wroot[k * 64 + lane];
        }
        float bv = bias[lane];
        int wave = (b - NBUK) * 8 + (tid >> 6);
        int nwaves = (gridDim.x - NBUK) * 8;
        if (wave == 0) tbf[(size_t)N_NODES * 64 + lane] = 0;   // zero clamp row (128B)
        for (int i = wave; i < N_NODES; i += nwaves) {
            float hv = x[i * 64 + lane];
            float tacc = 0.f, uacc = bv;
#pragma unroll
            for (int k = 0; k < 64; ++k) {
                float hk = bcastf(hv, k);
                tacc = fmaf(hk, wn[k], tacc);
                uacc = fmaf(hk, ws[k], uacc);
            }
            tbf[(size_t)i * 64 + lane] = f2h(tacc);
            ubf[(size_t)i * 64 + lane] = f2h(uacc);
        }
    }
}

// ---------------- clamp-free f16 gather-aggregate (R2-proven inner loop) ----------------
__device__ __forceinline__ uint2 ldrow(const ushort_t* __restrict__ tbf, int s, int q) {
    return *(const uint2*)(tbf + (size_t)s * 64 + q * 4);
}

// iv = prefetched first index chunk (csr[start + 4g .. +8B]); pads -> zero row.
// Per 16-edge chunk: issue 4 gathers, then next iv (hides under gather wait), accumulate.
__device__ __forceinline__ float4 agg_core_p(const ushort_t* __restrict__ tbf,
                                             const ushort_t* __restrict__ csr,
                                             int start, int deg, int g, int q, uint2 iv) {
    const ushort_t* cp = csr + start;          // start is 16-aligned
    hf2 l0{0,0}, l1{0,0}, l2{0,0}, l3{0,0};
    hf2 m0{0,0}, m1{0,0}, m2{0,0}, m3{0,0};
    int vr = (deg + 15) & ~15;
    for (int base = 0; base < vr; base += 16) {
        int s0 = (int)(iv.x & 0xFFFF);
        int s1 = (int)(iv.x >> 16);
        int s2 = (int)(iv.y & 0xFFFF);
        int s3 = (int)(iv.y >> 16);
        const uint2 w0 = ldrow(tbf, s0, q);
        const uint2 w1 = ldrow(tbf, s1, q);
        const uint2 w2 = ldrow(tbf, s2, q);
        const uint2 w3 = ldrow(tbf, s3, q);
        int nb = base + 16;
        iv = *(const uint2*)(cp + ((nb < vr) ? nb : 0) + 4 * g);  // prefetch next idx chunk
        l0 += u2h(w0.x); m0 += u2h(w0.y);
        l1 += u2h(w1.x); m1 += u2h(w1.y);
        l2 += u2h(w2.x); m2 += u2h(w2.y);
        l3 += u2h(w3.x); m3 += u2h(w3.y);
    }
    hf2 lo = (l0 + l1) + (l2 + l3);
    hf2 hi = (m0 + m1) + (m2 + m3);
    float4 acc = make_float4((float)lo.x, (float)lo.y, (float)hi.x, (float)hi.y);
    bfly(acc);
    return acc;
}

__device__ __forceinline__ float4 unpack_u2(uint2 uv) {
    hf2 a = u2h(uv.x), b = u2h(uv.y);
    return make_float4((float)a.x, (float)a.y, (float)b.x, (float)b.y);
}

// ---------------- fused: agg(layer k) [+ dout] + dot2-gemm(layer k+1) ----------------
// NPW=2 nodes per wave; launch_bounds(256,8) -> up to 8 blocks/CU resident.
__global__ __launch_bounds__(256, 8) void fused_kernel(const ushort_t* __restrict__ tin,
                                                       const ushort_t* __restrict__ uin,
                                                       const int2* __restrict__ row_info,
                                                       const ushort_t* __restrict__ csr,
                                                       const uint4* __restrict__ pwL,
                                                       const float* __restrict__ bias_next,
                                                       ushort_t* __restrict__ tout,
                                                       ushort_t* __restrict__ uout,
                                                       float* __restrict__ dout,
                                                       int use_mean) {
    __shared__ uint4 wlds[1024];   // [kp*16+q] Wn, +512 Ws; f16 pairs; linear (0 conflicts)
    __shared__ float blds[64];
    int tid = threadIdx.x;
    for (int i = tid; i < 1024; i += 256) wlds[i] = pwL[i];
    if (tid < 64) blds[tid] = bias_next[tid];
    if (blockIdx.x == 0 && tid < 32)       // zero clamp row of tout (128B)
        ((unsigned*)(tout + (size_t)N_NODES * 64))[tid] = 0;
    __syncthreads();
    int lane = tid & 63, g = lane >> 4, q = lane & 15;
    int w = blockIdx.x * 4 + (tid >> 6);

    // hoist: all NPW nodes' row_info, first csr idx chunk, and u rows (independent loads)
    int2 ri[NPW];
    uint2 iv0[NPW];
    uint2 uvp[NPW];
#pragma unroll
    for (int i = 0; i < NPW; ++i) ri[i] = row_info[w + FWAVES * i];     // 2*25000=50000 exact
#pragma unroll
    for (int i = 0; i < NPW; ++i) iv0[i] = *(const uint2*)(csr + ri[i].x + 4 * g);
#pragma unroll
    for (int i = 0; i < NPW; ++i)
        uvp[i] = *(const uint2*)(uin + (size_t)(w + FWAVES * i) * 64 + q * 4);

#pragma unroll
    for (int i = 0; i < NPW; ++i) {
        int node = w + FWAVES * i;
        float4 acc = agg_core_p(tin, csr, ri[i].x, ri[i].y, g, q, iv0[i]);
        float sc = use_mean ? 1.f / fmaxf((float)ri[i].y, 1.f) : 1.f;
        const float4 uv = unpack_u2(uvp[i]);
        float4 h;
        h.x = fmaxf(uv.x + acc.x * sc, 0.f);
        h.y = fmaxf(uv.y + acc.y * sc, 0.f);
        h.z = fmaxf(uv.z + acc.z * sc, 0.f);
        h.w = fmaxf(uv.w + acc.w * sc, 0.f);
        if (dout && g == 0)                // NT: dout never re-read by this dispatch
            ntst4(dout + (size_t)node * 64 + q * 4, h.x, h.y, h.z, h.w);
        // pack h into f16 k-pairs: lane q holds kp=2q (h.x,h.y) and kp=2q+1 (h.z,h.w)
        int hp_lo = (int)pkh(h.x, h.y);
        int hp_hi = (int)pkh(h.z, h.w);
        // dot2 gemm: group g covers kp in [8g, 8g+8)
        float4 tp{0,0,0,0}, up{0,0,0,0};
#pragma unroll
        for (int jp = 0; jp < 8; ++jp) {
            int kp = 8 * g + jp;
            const uint4 wvn = wlds[kp * 16 + q];
            const uint4 wvs = wlds[512 + kp * 16 + q];
            int srcl = 4 * g + (jp >> 1);
            unsigned hu = (unsigned)__shfl((jp & 1) ? hp_hi : hp_lo, srcl);
            hf2 hh = u2h(hu);
            tp.x = __builtin_amdgcn_fdot2(hh, u2h(wvn.x), tp.x, false);
            tp.y = __builtin_amdgcn_fdot2(hh, u2h(wvn.y), tp.y, false);
            tp.z = __builtin_amdgcn_fdot2(hh, u2h(wvn.z), tp.z, false);
            tp.w = __builtin_amdgcn_fdot2(hh, u2h(wvn.w), tp.w, false);
            up.x = __builtin_amdgcn_fdot2(hh, u2h(wvs.x), up.x, false);
            up.y = __builtin_amdgcn_fdot2(hh, u2h(wvs.y), up.y, false);
            up.z = __builtin_amdgcn_fdot2(hh, u2h(wvs.z), up.z, false);
            up.w = __builtin_amdgcn_fdot2(hh, u2h(wvs.w), up.w, false);
        }
        bfly(tp); bfly(up);
        if (g == 0) {
            const float4 bv = *(const float4*)&blds[q * 4];
            uint2 upk, tpk;
            upk.x = pkh(up.x + bv.x, up.y + bv.y);
            upk.y = pkh(up.z + bv.z, up.w + bv.w);
            tpk.x = pkh(tp.x, tp.y);
            tpk.y = pkh(tp.z, tp.w);
            *(uint2*)(uout + (size_t)node * 64 + q * 4) = upk;
            *(uint2*)(tout + (size_t)node * 64 + q * 4) = tpk;
        }
    }
}

// ---------------- final agg-only ----------------
__global__ __launch_bounds__(256, 8) void agg_kernel(const ushort_t* __restrict__ tbf,
                                                     const ushort_t* __restrict__ ubf,
                                                     const int2* __restrict__ row_info,
                                                     const ushort_t* __restrict__ csr,
                                                     float* __restrict__ out, int use_mean) {
    int lane = threadIdx.x & 63;
    int g = lane >> 4, q = lane & 15;
    int node = (blockIdx.x * 256 + threadIdx.x) >> 6;
    if (node >= N_NODES) return;
    int2 ri = row_info[node];
    uint2 iv0 = *(const uint2*)(csr + ri.x + 4 * g);
    float4 acc = agg_core_p(tbf, csr, ri.x, ri.y, g, q, iv0);
    float scale = use_mean ? 1.f / fmaxf((float)ri.y, 1.f) : 1.f;
    if (g == 0) {
        const uint2 uvr = *(const uint2*)(ubf + (size_t)node * 64 + q * 4);
        const float4 uv = unpack_u2(uvr);
        float rx = fmaxf(uv.x + acc.x * scale, 0.f);
        float ry = fmaxf(uv.y + acc.y * scale, 0.f);
        float rz = fmaxf(uv.z + acc.z * scale, 0.f);
        float rw = fmaxf(uv.w + acc.w * scale, 0.f);
        ntst4(out + (size_t)node * 64 + q * 4, rx, ry, rz, rw);
    }
}

// ---------------- launch: 7 dispatches ----------------
extern "C" void kernel_launch(void* const* d_in, const int* in_sizes, int n_in,
                              void* d_out, int out_size, void* d_ws, size_t ws_size,
                              hipStream_t stream) {
    const float* x      = (const float*)d_in[0];
    const int*   ei     = (const int*)d_in[1];
    const float* Wrel1  = (const float*)d_in[2];
    const float* Wroot1 = (const float*)d_in[3];
    const float* b1     = (const float*)d_in[4];
    const float* Wself2 = (const float*)d_in[5];
    const float* Wnbr2  = (const float*)d_in[6];
    const float* b2     = (const float*)d_in[7];
    const float* Wself3 = (const float*)d_in[8];
    const float* Wnbr3  = (const float*)d_in[9];
    const float* b3     = (const float*)d_in[10];
    const float* Wself4 = (const float*)d_in[11];
    const float* Wnbr4  = (const float*)d_in[12];
    const float* b4     = (const float*)d_in[13];

    const int N = N_NODES, E = N_EDGES;

    auto align = [](size_t o) { return (o + 255) & ~(size_t)255; };
    char* base = (char*)d_ws;
    size_t off = 0;
    int*  cursor   = (int*)(base + off);  off = align(off + (size_t)NBUK * 4);
    int2* row_info = (int2*)(base + off); off = align(off + (size_t)N * 8);
    int*  tmp      = (int*)(base + off);  off = align(off + (size_t)NBUK * PAD2 * 4);
    ushort_t* csr  = (ushort_t*)(base + off); off = align(off + (size_t)NBUK * PAD2 * 2 + 1024);
    uint4* pw      = (uint4*)(base + off);    off = align(off + (size_t)3 * 1024 * 16);
    ushort_t* tbA  = (ushort_t*)(base + off); off = align(off + (size_t)(N + 1) * 64 * 2);
    ushort_t* tbB  = (ushort_t*)(base + off); off = align(off + (size_t)(N + 1) * 64 * 2);
    ushort_t* ubA  = (ushort_t*)(base + off); off = align(off + (size_t)N * 64 * 2);
    ushort_t* ubB  = (ushort_t*)(base + off); off = align(off + (size_t)N * 64 * 2);

    float* out1 = (float*)d_out;
    float* out2 = (float*)d_out + (size_t)N * 64;

    // 1) cursor init + W f16 packing
    init_kernel<<<4, 512, 0, stream>>>(cursor, Wnbr2, Wself2, Wnbr3, Wself3, Wnbr4, Wself4, pw);
    // 2) bucket scatter
    scatter_fused_kernel<<<GBIN, 256, 0, stream>>>(ei, cursor, tmp, E);
    // 3) per-bucket counting sort (16-aligned, zero-row pads) || gemm1 -> t1(tbA), u1(ubA)
    bucketize_kernel<<<NBUK + 1024, 512, 0, stream>>>(tmp, cursor, row_info, csr,
                                                      x, Wrel1, Wroot1, b1, tbA, ubA);
    // 4) F1: agg1(mean) + gemm2 -> t2(tbB), u2(ubB)
    fused_kernel<<<FBLK, 256, 0, stream>>>(tbA, ubA, row_info, csr, pw,        b2, tbB, ubB, nullptr, 1);
    // 5) F2: agg2 -> out1, + gemm3 -> t3(tbA), u3(ubA)
    fused_kernel<<<FBLK, 256, 0, stream>>>(tbB, ubB, row_info, csr, pw + 1024, b3, tbA, ubA, out1, 0);
    // 6) F3: agg3 + gemm4 -> t4(tbB), u4(ubB)
    fused_kernel<<<FBLK, 256, 0, stream>>>(tbA, ubA, row_info, csr, pw + 2048, b4, tbB, ubB, nullptr, 0);
    // 7) F4: agg4 -> out2
    agg_kernel<<<(N + 3) / 4, 256, 0, stream>>>(tbB, ubB, row_info, csr, out2, 0);
}